// Round 1
// baseline (7571.355 us; speedup 1.0000x reference)
//
#include <hip/hip_runtime.h>
#include <math.h>

constexpr int NLAYER = 12;
constexpr int H = 768;
constexpr int NH = 12;
constexpr int DH = 64;
constexpr int T = 512;
constexpr int B = 4;
constexpr int K = 21;
constexpr int BT = B * T;                 // 2048 token rows
constexpr float NEGB = -10000.0f;
constexpr float LNEPS = 1e-12f;
constexpr float INV_SQRT_DH = 0.125f;

// ---------------- reduction helpers ----------------
__device__ __forceinline__ float wave_sum_f(float v) {
#pragma unroll
  for (int off = 32; off > 0; off >>= 1) v += __shfl_xor(v, off);
  return v;
}
__device__ __forceinline__ int wave_sum_i(int v) {
#pragma unroll
  for (int off = 32; off > 0; off >>= 1) v += __shfl_xor(v, off);
  return v;
}

// 256-thread block: reduce (sum, sumsq); result broadcast to all threads
__device__ __forceinline__ void block_reduce_sum2(float& s, float& q) {
  __shared__ float red[8];
  s = wave_sum_f(s);
  q = wave_sum_f(q);
  int lane = threadIdx.x & 63, wid = threadIdx.x >> 6;
  if (lane == 0) { red[wid] = s; red[4 + wid] = q; }
  __syncthreads();
  s = red[0] + red[1] + red[2] + red[3];
  q = red[4] + red[5] + red[6] + red[7];
}

// ---------------- embedding + LN ----------------
__global__ __launch_bounds__(256) void embed_ln_kernel(
    const int* __restrict__ ids, const float* __restrict__ wemb,
    const float* __restrict__ pemb, const float* __restrict__ temb,
    const float* __restrict__ g, const float* __restrict__ bta,
    float* __restrict__ h) {
  int row = blockIdx.x;
  int t = row % T;
  int id = ids[row];
  const float* wp = wemb + (size_t)id * H;
  const float* pp = pemb + (size_t)t * H;
  float x[3];
  float s = 0.f, q = 0.f;
#pragma unroll
  for (int i = 0; i < 3; i++) {
    int c = threadIdx.x + i * 256;
    x[i] = wp[c] + pp[c] + temb[c];
    s += x[i];
    q += x[i] * x[i];
  }
  block_reduce_sum2(s, q);
  float mean = s * (1.0f / H);
  float var = q * (1.0f / H) - mean * mean;
  float inv = rsqrtf(var + LNEPS);
#pragma unroll
  for (int i = 0; i < 3; i++) {
    int c = threadIdx.x + i * 256;
    h[(size_t)row * H + c] = (x[i] - mean) * inv * g[c] + bta[c];
  }
}

// ---------------- residual add + LN (in place on h) ----------------
__global__ __launch_bounds__(256) void add_ln_kernel(
    float* __restrict__ h, const float* __restrict__ add,
    const float* __restrict__ g, const float* __restrict__ bta) {
  int row = blockIdx.x;
  size_t base = (size_t)row * H;
  float x[3];
  float s = 0.f, q = 0.f;
#pragma unroll
  for (int i = 0; i < 3; i++) {
    int c = threadIdx.x + i * 256;
    x[i] = h[base + c] + add[base + c];
    s += x[i];
    q += x[i] * x[i];
  }
  block_reduce_sum2(s, q);
  float mean = s * (1.0f / H);
  float var = q * (1.0f / H) - mean * mean;
  float inv = rsqrtf(var + LNEPS);
#pragma unroll
  for (int i = 0; i < 3; i++) {
    int c = threadIdx.x + i * 256;
    h[base + c] = (x[i] - mean) * inv * g[c] + bta[c];
  }
}

// ---------------- GEMM: C[M,N] = A[M,Kd] * W[Kd,N] + bias, 128x64 tile ----------------
__global__ __launch_bounds__(256) void gemm128x64_kernel(
    const float* __restrict__ A, const float* __restrict__ W,
    const float* __restrict__ bias, float* __restrict__ C, int N, int Kd) {
  __shared__ float As[16][128];
  __shared__ float Bs[16][64];
  int tid = threadIdx.x;
  int bm = blockIdx.y * 128, bn = blockIdx.x * 64;
  int tx = tid & 15, ty = tid >> 4;
  int arow = tid & 127;
  int akseg = (tid >> 7) * 8;
  int brow = tid >> 4;
  int bcol = (tid & 15) * 4;
  float acc[8][4] = {};
  const float* Arow = A + (size_t)(bm + arow) * Kd;
  for (int k0 = 0; k0 < Kd; k0 += 16) {
    float4 a0 = *(const float4*)(Arow + k0 + akseg);
    float4 a1 = *(const float4*)(Arow + k0 + akseg + 4);
    float4 bv = *(const float4*)(W + (size_t)(k0 + brow) * N + bn + bcol);
    __syncthreads();
    As[akseg + 0][arow] = a0.x; As[akseg + 1][arow] = a0.y;
    As[akseg + 2][arow] = a0.z; As[akseg + 3][arow] = a0.w;
    As[akseg + 4][arow] = a1.x; As[akseg + 5][arow] = a1.y;
    As[akseg + 6][arow] = a1.z; As[akseg + 7][arow] = a1.w;
    *(float4*)&Bs[brow][bcol] = bv;
    __syncthreads();
#pragma unroll
    for (int kk = 0; kk < 16; kk++) {
      float a_[8], b_[4];
      *(float4*)&a_[0] = *(const float4*)&As[kk][ty * 8];
      *(float4*)&a_[4] = *(const float4*)&As[kk][ty * 8 + 4];
      *(float4*)&b_[0] = *(const float4*)&Bs[kk][tx * 4];
#pragma unroll
      for (int i = 0; i < 8; i++)
#pragma unroll
        for (int j = 0; j < 4; j++)
          acc[i][j] = fmaf(a_[i], b_[j], acc[i][j]);
    }
  }
#pragma unroll
  for (int i = 0; i < 8; i++) {
    int m = bm + ty * 8 + i;
    int n = bn + tx * 4;
    float4 o;
    o.x = acc[i][0] + bias[n + 0];
    o.y = acc[i][1] + bias[n + 1];
    o.z = acc[i][2] + bias[n + 2];
    o.w = acc[i][3] + bias[n + 3];
    *(float4*)(C + (size_t)m * N + n) = o;
  }
}

// ---------------- GEMM 64x64 tile (for N=768 projections) ----------------
__global__ __launch_bounds__(256) void gemm64_kernel(
    const float* __restrict__ A, const float* __restrict__ W,
    const float* __restrict__ bias, float* __restrict__ C, int N, int Kd) {
  __shared__ float As[16][64];
  __shared__ float Bs[16][64];
  int tid = threadIdx.x;
  int bm = blockIdx.y * 64, bn = blockIdx.x * 64;
  int tx = tid & 15, ty = tid >> 4;
  int arow = tid >> 2;
  int akseg = (tid & 3) * 4;
  int brow = tid >> 4;
  int bcol = (tid & 15) * 4;
  float acc[4][4] = {};
  const float* Arow = A + (size_t)(bm + arow) * Kd;
  for (int k0 = 0; k0 < Kd; k0 += 16) {
    float4 av = *(const float4*)(Arow + k0 + akseg);
    float4 bv = *(const float4*)(W + (size_t)(k0 + brow) * N + bn + bcol);
    __syncthreads();
    As[akseg + 0][arow] = av.x; As[akseg + 1][arow] = av.y;
    As[akseg + 2][arow] = av.z; As[akseg + 3][arow] = av.w;
    *(float4*)&Bs[brow][bcol] = bv;
    __syncthreads();
#pragma unroll
    for (int kk = 0; kk < 16; kk++) {
      float a_[4], b_[4];
      *(float4*)&a_[0] = *(const float4*)&As[kk][ty * 4];
      *(float4*)&b_[0] = *(const float4*)&Bs[kk][tx * 4];
#pragma unroll
      for (int i = 0; i < 4; i++)
#pragma unroll
        for (int j = 0; j < 4; j++)
          acc[i][j] = fmaf(a_[i], b_[j], acc[i][j]);
    }
  }
#pragma unroll
  for (int i = 0; i < 4; i++) {
    int m = bm + ty * 4 + i;
    int n = bn + tx * 4;
    float4 o;
    o.x = acc[i][0] + bias[n + 0];
    o.y = acc[i][1] + bias[n + 1];
    o.z = acc[i][2] + bias[n + 2];
    o.w = acc[i][3] + bias[n + 3];
    *(float4*)(C + (size_t)m * N + n) = o;
  }
}

// ---------------- S = Q K^T * scale + mask bias ----------------
__global__ __launch_bounds__(256) void qk_kernel(
    const float* __restrict__ qkv, const int* __restrict__ mask,
    float* __restrict__ S) {
  int bh = blockIdx.z;
  int b = bh / NH, hh = bh % NH;
  int i0 = blockIdx.y * 64, j0 = blockIdx.x * 64;
  __shared__ float Qs[64][64];  // [d][i]
  __shared__ float Ks[64][64];  // [d][j]
  int tid = threadIdx.x;
  int r = tid >> 2;
  int cseg = (tid & 3) * 16;
  const float* qbase = qkv + (size_t)(b * T + i0 + r) * (3 * H) + hh * DH;
  const float* kbase = qkv + (size_t)(b * T + j0 + r) * (3 * H) + H + hh * DH;
#pragma unroll
  for (int ss = 0; ss < 4; ss++) {
    int c = cseg + ss * 4;
    float4 qa = *(const float4*)(qbase + c);
    float4 ka = *(const float4*)(kbase + c);
    Qs[c + 0][r] = qa.x; Qs[c + 1][r] = qa.y; Qs[c + 2][r] = qa.z; Qs[c + 3][r] = qa.w;
    Ks[c + 0][r] = ka.x; Ks[c + 1][r] = ka.y; Ks[c + 2][r] = ka.z; Ks[c + 3][r] = ka.w;
  }
  __syncthreads();
  int tx = tid & 15, ty = tid >> 4;
  float acc[4][4] = {};
#pragma unroll 4
  for (int d = 0; d < 64; d++) {
    float a_[4], b_[4];
    *(float4*)a_ = *(const float4*)&Qs[d][ty * 4];
    *(float4*)b_ = *(const float4*)&Ks[d][tx * 4];
#pragma unroll
    for (int i = 0; i < 4; i++)
#pragma unroll
      for (int j = 0; j < 4; j++)
        acc[i][j] = fmaf(a_[i], b_[j], acc[i][j]);
  }
  float bj[4];
#pragma unroll
  for (int q = 0; q < 4; q++)
    bj[q] = (1.0f - (float)mask[b * T + j0 + tx * 4 + q]) * NEGB;
#pragma unroll
  for (int i = 0; i < 4; i++) {
    int gi = i0 + ty * 4 + i;
    int gj = j0 + tx * 4;
    float4 o;
    o.x = acc[i][0] * INV_SQRT_DH + bj[0];
    o.y = acc[i][1] * INV_SQRT_DH + bj[1];
    o.z = acc[i][2] * INV_SQRT_DH + bj[2];
    o.w = acc[i][3] * INV_SQRT_DH + bj[3];
    *(float4*)(S + ((size_t)bh * T + gi) * T + gj) = o;
  }
}

// ---------------- row softmax over 512 ----------------
__global__ __launch_bounds__(128) void softmax_kernel(float* __restrict__ S) {
  size_t row = blockIdx.x;
  float* p = S + row * T;
  int tid = threadIdx.x;
  float4 v = *(float4*)(p + tid * 4);
  float m = fmaxf(fmaxf(v.x, v.y), fmaxf(v.z, v.w));
#pragma unroll
  for (int off = 32; off > 0; off >>= 1) m = fmaxf(m, __shfl_xor(m, off));
  __shared__ float redm[2];
  __shared__ float reds[2];
  int wid = tid >> 6;
  if ((tid & 63) == 0) redm[wid] = m;
  __syncthreads();
  m = fmaxf(redm[0], redm[1]);
  v.x = __expf(v.x - m);
  v.y = __expf(v.y - m);
  v.z = __expf(v.z - m);
  v.w = __expf(v.w - m);
  float s = v.x + v.y + v.z + v.w;
  s = wave_sum_f(s);
  if ((tid & 63) == 0) reds[wid] = s;
  __syncthreads();
  s = reds[0] + reds[1];
  float inv = 1.0f / s;
  v.x *= inv; v.y *= inv; v.z *= inv; v.w *= inv;
  *(float4*)(p + tid * 4) = v;
}

// ---------------- ctx = P * V ----------------
__global__ __launch_bounds__(256) void pv_kernel(
    const float* __restrict__ S, const float* __restrict__ qkv,
    float* __restrict__ ctx) {
  int bh = blockIdx.y;
  int b = bh / NH, hh = bh % NH;
  int i0 = blockIdx.x * 64;
  __shared__ float Ps[64][68];  // [i][k], padded
  __shared__ float Vs[64][64];  // [k][d]
  int tid = threadIdx.x;
  int r = tid >> 2;
  int cseg = (tid & 3) * 16;
  int tx = tid & 15, ty = tid >> 4;
  float acc[4][4] = {};
  const float* srow = S + ((size_t)bh * T + i0 + r) * T;
  const float* vbase = qkv + (size_t)(b * T) * (3 * H) + 2 * H + hh * DH;
  for (int k0 = 0; k0 < T; k0 += 64) {
    __syncthreads();
#pragma unroll
    for (int ss = 0; ss < 4; ss++) {
      int c = cseg + ss * 4;
      *(float4*)&Ps[r][c] = *(const float4*)(srow + k0 + c);
      *(float4*)&Vs[r][c] = *(const float4*)(vbase + (size_t)(k0 + r) * (3 * H) + c);
    }
    __syncthreads();
#pragma unroll
    for (int kk = 0; kk < 64; kk += 4) {
      float p_[4][4], v_[4][4];
#pragma unroll
      for (int i = 0; i < 4; i++)
        *(float4*)p_[i] = *(const float4*)&Ps[ty * 4 + i][kk];
#pragma unroll
      for (int s = 0; s < 4; s++)
        *(float4*)v_[s] = *(const float4*)&Vs[kk + s][tx * 4];
#pragma unroll
      for (int i = 0; i < 4; i++)
#pragma unroll
        for (int s = 0; s < 4; s++)
#pragma unroll
          for (int j = 0; j < 4; j++)
            acc[i][j] = fmaf(p_[i][s], v_[s][j], acc[i][j]);
    }
  }
#pragma unroll
  for (int i = 0; i < 4; i++) {
    int gi = i0 + ty * 4 + i;
    float* cp = ctx + (size_t)(b * T + gi) * H + hh * DH + tx * 4;
    float4 o;
    o.x = acc[i][0]; o.y = acc[i][1]; o.z = acc[i][2]; o.w = acc[i][3];
    *(float4*)cp = o;
  }
}

// ---------------- exact GELU ----------------
__global__ __launch_bounds__(256) void gelu_kernel(float* __restrict__ x, int n4) {
  int i = blockIdx.x * 256 + threadIdx.x;
  if (i >= n4) return;
  float4 v = ((float4*)x)[i];
  v.x = 0.5f * v.x * (1.0f + erff(v.x * 0.70710678118654752f));
  v.y = 0.5f * v.y * (1.0f + erff(v.y * 0.70710678118654752f));
  v.z = 0.5f * v.z * (1.0f + erff(v.z * 0.70710678118654752f));
  v.w = 0.5f * v.w * (1.0f + erff(v.w * 0.70710678118654752f));
  ((float4*)x)[i] = v;
}

// ---------------- classifier: emissions = h @ Wc + bc ----------------
__global__ __launch_bounds__(256) void classifier_kernel(
    const float* __restrict__ h, const float* __restrict__ Wc,
    const float* __restrict__ bc, float* __restrict__ em) {
  int id = blockIdx.x * 256 + threadIdx.x;
  if (id >= BT * K) return;
  int row = id / K, k = id % K;
  float acc = bc[k];
  const float* hr = h + (size_t)row * H;
  for (int d = 0; d < H; d++) acc = fmaf(hr[d], Wc[d * K + k], acc);
  em[id] = acc;
}

// ---------------- CRF forward (nll parts per batch) ----------------
__global__ __launch_bounds__(64) void crf_nll_kernel(
    const float* __restrict__ em, const int* __restrict__ labels,
    const int* __restrict__ mask, const float* __restrict__ start,
    const float* __restrict__ endv, const float* __restrict__ trans,
    float* __restrict__ parts) {
  int b = blockIdx.x;
  int j = threadIdx.x;
  const float* eb = em + (size_t)b * T * K;
  const int* mb = mask + b * T;
  const int* tb = labels + b * T;
  bool act = (j < K);

  // ---- numerator (parallel over t) ----
  float numloc = 0.f;
  int cnt = 0;
  for (int t = j; t < T; t += 64) {
    cnt += mb[t];
    if (t >= 1 && mb[t]) {
      int tp = tb[t - 1], tc = tb[t];
      numloc += trans[tp * K + tc] + eb[(size_t)t * K + tc];
    }
  }
  float num = wave_sum_f(numloc);
  int cnttot = wave_sum_i(cnt);

  // ---- forward recursion ----
  float tr[K];
  if (act) {
#pragma unroll
    for (int i = 0; i < K; i++) tr[i] = trans[i * K + j];
  } else {
#pragma unroll
    for (int i = 0; i < K; i++) tr[i] = 0.f;
  }
  float alpha = -3.0e38f;
  if (act) alpha = start[j] + eb[j];
  for (int t = 1; t < T; t++) {
    if (mb[t]) {
      float vals[K];
      float m = -3.0e38f;
#pragma unroll
      for (int i = 0; i < K; i++) {
        float v = __shfl(alpha, i) + tr[i];
        vals[i] = v;
        m = fmaxf(m, v);
      }
      float ssum = 0.f;
#pragma unroll
      for (int i = 0; i < K; i++) ssum += __expf(vals[i] - m);
      float emv = 0.f;
      if (act) emv = eb[(size_t)t * K + j];
      float nxt = __logf(ssum) + m + emv;
      if (act) alpha = nxt;
    }
  }
  // den = logsumexp(alpha + end)
  float aj = -3.0e38f;
  if (act) aj = alpha + endv[j];
  float mm = aj;
#pragma unroll
  for (int off = 32; off > 0; off >>= 1) mm = fmaxf(mm, __shfl_xor(mm, off));
  float e = act ? __expf(aj - mm) : 0.f;
  float s = wave_sum_f(e);
  float den = __logf(s) + mm;
  if (j == 0) {
    int tag0 = tb[0];
    int lastidx = cnttot - 1;
    float numtot = num + start[tag0] + eb[tag0] + endv[tb[lastidx]];
    parts[b] = numtot - den;
  }
}

__global__ void nll_final_kernel(const float* __restrict__ parts,
                                 float* __restrict__ out) {
  out[0] = -0.25f * (parts[0] + parts[1] + parts[2] + parts[3]);
}

// ---------------- Viterbi decode ----------------
__global__ __launch_bounds__(64) void viterbi_kernel(
    const float* __restrict__ em, const int* __restrict__ mask,
    const float* __restrict__ start, const float* __restrict__ endv,
    const float* __restrict__ trans, int* __restrict__ hist,
    float* __restrict__ outdec) {
  int b = blockIdx.x;
  int j = threadIdx.x;
  const float* eb = em + (size_t)b * T * K;
  const int* mb = mask + b * T;
  bool act = (j < K);
  float tr[K];
  if (act) {
#pragma unroll
    for (int i = 0; i < K; i++) tr[i] = trans[i * K + j];
  } else {
#pragma unroll
    for (int i = 0; i < K; i++) tr[i] = 0.f;
  }
  float score = -3.0e38f;
  if (act) score = start[j] + eb[j];
  for (int t = 1; t < T; t++) {
    int m = mb[t];
    float best = -3.0e38f;
    int bi = 0;
#pragma unroll
    for (int i = 0; i < K; i++) {
      float v = __shfl(score, i) + tr[i];
      if (v > best) { best = v; bi = i; }   // first-max (jnp.argmax semantics)
    }
    if (act) {
      int idx = m ? bi : j;
      hist[(size_t)(t - 1) * (B * K) + b * K + j] = idx;
      if (m) score = best + eb[(size_t)t * K + j];
    }
  }
  __shared__ float sc[K];
  if (act) sc[j] = score + endv[j];
  __syncthreads();
  if (j == 0) {
    float best = -3.0e38f;
    int last = 0;
#pragma unroll
    for (int i = 0; i < K; i++)
      if (sc[i] > best) { best = sc[i]; last = i; }
    int cur = last;
    outdec[b * T + (T - 1)] = (float)cur;
    for (int t = T - 1; t >= 1; t--) {
      cur = hist[(size_t)(t - 1) * (B * K) + b * K + cur];
      outdec[b * T + (t - 1)] = (float)cur;
    }
  }
}

// ---------------- host launcher ----------------
extern "C" void kernel_launch(void* const* d_in, const int* in_sizes, int n_in,
                              void* d_out, int out_size, void* d_ws, size_t ws_size,
                              hipStream_t stream) {
  (void)in_sizes; (void)n_in; (void)out_size; (void)ws_size;
  const int* ids    = (const int*)d_in[0];
  const int* amask  = (const int*)d_in[1];
  // d_in[2] valid_mask unused by reference outputs
  const int* labels = (const int*)d_in[3];
  const float* wemb = (const float*)d_in[4];
  const float* pemb = (const float*)d_in[5];
  const float* temb = (const float*)d_in[6];
  const float* eg   = (const float*)d_in[7];
  const float* ebta = (const float*)d_in[8];
  const float* Wqkv = (const float*)d_in[9];
  const float* bqkv = (const float*)d_in[10];
  const float* Wo   = (const float*)d_in[11];
  const float* bo   = (const float*)d_in[12];
  const float* ln1g = (const float*)d_in[13];
  const float* ln1b = (const float*)d_in[14];
  const float* W1   = (const float*)d_in[15];
  const float* b1   = (const float*)d_in[16];
  const float* W2   = (const float*)d_in[17];
  const float* b2   = (const float*)d_in[18];
  const float* ln2g = (const float*)d_in[19];
  const float* ln2b = (const float*)d_in[20];
  const float* Wc   = (const float*)d_in[21];
  const float* bc   = (const float*)d_in[22];
  const float* cst  = (const float*)d_in[23];
  const float* cen  = (const float*)d_in[24];
  const float* ctr  = (const float*)d_in[25];
  float* out = (float*)d_out;

  // workspace layout (floats)
  float* ws   = (float*)d_ws;
  float* h    = ws;                         // 2048*768       = 1,572,864
  float* qkv  = h + (size_t)BT * H;         // 2048*2304      = 4,718,592
  float* ctx  = qkv + (size_t)BT * 3 * H;   // 2048*768
  float* tmp  = ctx + (size_t)BT * H;       // 2048*768
  float* big  = tmp + (size_t)BT * H;       // max(scores 12.58M, ffn 6.29M)
  float* em   = big + (size_t)B * NH * T * T;  // 2048*21
  float* parts = em + (size_t)BT * K;       // 8
  int*   hist = (int*)(parts + 8);          // 511*4*21 ints
  // total ~ 88.4 MB

  embed_ln_kernel<<<BT, 256, 0, stream>>>(ids, wemb, pemb, temb, eg, ebta, h);

  for (int l = 0; l < NLAYER; l++) {
    const float* wqkv_l = Wqkv + (size_t)l * H * 3 * H;
    const float* bqkv_l = bqkv + (size_t)l * 3 * H;
    const float* wo_l   = Wo + (size_t)l * H * H;
    const float* bo_l   = bo + (size_t)l * H;
    const float* w1_l   = W1 + (size_t)l * H * 4 * H;
    const float* b1_l   = b1 + (size_t)l * 4 * H;
    const float* w2_l   = W2 + (size_t)l * 4 * H * H;
    const float* b2_l   = b2 + (size_t)l * H;

    // qkv = h @ Wqkv + bqkv
    gemm128x64_kernel<<<dim3(3 * H / 64, BT / 128), 256, 0, stream>>>(
        h, wqkv_l, bqkv_l, qkv, 3 * H, H);
    // S = QK^T*scale + bias
    qk_kernel<<<dim3(T / 64, T / 64, B * NH), 256, 0, stream>>>(qkv, amask, big);
    softmax_kernel<<<B * NH * T, 128, 0, stream>>>(big);
    pv_kernel<<<dim3(T / 64, B * NH), 256, 0, stream>>>(big, qkv, ctx);
    // attn out proj
    gemm64_kernel<<<dim3(H / 64, BT / 64), 256, 0, stream>>>(
        ctx, wo_l, bo_l, tmp, H, H);
    add_ln_kernel<<<BT, 256, 0, stream>>>(h, tmp, ln1g + (size_t)l * H, ln1b + (size_t)l * H);
    // FFN
    gemm128x64_kernel<<<dim3(4 * H / 64, BT / 128), 256, 0, stream>>>(
        h, w1_l, b1_l, big, 4 * H, H);
    gelu_kernel<<<(BT * 4 * H / 4 + 255) / 256, 256, 0, stream>>>(big, BT * 4 * H / 4);
    gemm64_kernel<<<dim3(H / 64, BT / 64), 256, 0, stream>>>(
        big, w2_l, b2_l, tmp, H, 4 * H);
    add_ln_kernel<<<BT, 256, 0, stream>>>(h, tmp, ln2g + (size_t)l * H, ln2b + (size_t)l * H);
  }

  classifier_kernel<<<(BT * K + 255) / 256, 256, 0, stream>>>(h, Wc, bc, em);
  crf_nll_kernel<<<B, 64, 0, stream>>>(em, labels, amask, cst, cen, ctr, parts);
  nll_final_kernel<<<1, 1, 0, stream>>>(parts, out);
  viterbi_kernel<<<B, 64, 0, stream>>>(em, amask, cst, cen, ctr, hist, out + 1);
}

// Round 2
// 3934.509 us; speedup vs baseline: 1.9243x; 1.9243x over previous
//
#include <hip/hip_runtime.h>
#include <math.h>

constexpr int NLAYER = 12;
constexpr int H = 768;
constexpr int NH = 12;
constexpr int DH = 64;
constexpr int T = 512;
constexpr int B = 4;
constexpr int K = 21;
constexpr int BT = B * T;
constexpr float NEGB = -10000.0f;
constexpr float LNEPS = 1e-12f;
constexpr float INV_SQRT_DH = 0.125f;

typedef __attribute__((ext_vector_type(8))) short bf16x8;
typedef __attribute__((ext_vector_type(4))) float f32x4;

// ---------------- helpers ----------------
__device__ __forceinline__ float wave_sum_f(float v) {
#pragma unroll
  for (int off = 32; off > 0; off >>= 1) v += __shfl_xor(v, off);
  return v;
}
__device__ __forceinline__ int wave_sum_i(int v) {
#pragma unroll
  for (int off = 32; off > 0; off >>= 1) v += __shfl_xor(v, off);
  return v;
}

__device__ __forceinline__ unsigned short f32_bf16_rn(float x) {
  unsigned int u = __float_as_uint(x);
  u += 0x7fffu + ((u >> 16) & 1u);
  return (unsigned short)(u >> 16);
}
__device__ __forceinline__ void split_bf16(float x, unsigned short& h, unsigned short& l) {
  h = f32_bf16_rn(x);
  float hf = __uint_as_float((unsigned int)h << 16);
  l = f32_bf16_rn(x - hf);
}

__device__ __forceinline__ void block_reduce_sum2(float& s, float& q) {
  __shared__ float red[8];
  s = wave_sum_f(s);
  q = wave_sum_f(q);
  int lane = threadIdx.x & 63, wid = threadIdx.x >> 6;
  if (lane == 0) { red[wid] = s; red[4 + wid] = q; }
  __syncthreads();
  s = red[0] + red[1] + red[2] + red[3];
  q = red[4] + red[5] + red[6] + red[7];
}

// ---------------- embedding + LN ----------------
__global__ __launch_bounds__(256) void embed_ln_kernel(
    const int* __restrict__ ids, const float* __restrict__ wemb,
    const float* __restrict__ pemb, const float* __restrict__ temb,
    const float* __restrict__ g, const float* __restrict__ bta,
    float* __restrict__ h) {
  int row = blockIdx.x;
  int t = row % T;
  int id = ids[row];
  const float* wp = wemb + (size_t)id * H;
  const float* pp = pemb + (size_t)t * H;
  float x[3];
  float s = 0.f, q = 0.f;
#pragma unroll
  for (int i = 0; i < 3; i++) {
    int c = threadIdx.x + i * 256;
    x[i] = wp[c] + pp[c] + temb[c];
    s += x[i];
    q += x[i] * x[i];
  }
  block_reduce_sum2(s, q);
  float mean = s * (1.0f / H);
  float var = q * (1.0f / H) - mean * mean;
  float inv = rsqrtf(var + LNEPS);
#pragma unroll
  for (int i = 0; i < 3; i++) {
    int c = threadIdx.x + i * 256;
    h[(size_t)row * H + c] = (x[i] - mean) * inv * g[c] + bta[c];
  }
}

// ---------------- residual add + LN ----------------
__global__ __launch_bounds__(256) void add_ln_kernel(
    float* __restrict__ h, const float* __restrict__ add,
    const float* __restrict__ g, const float* __restrict__ bta) {
  int row = blockIdx.x;
  size_t base = (size_t)row * H;
  float x[3];
  float s = 0.f, q = 0.f;
#pragma unroll
  for (int i = 0; i < 3; i++) {
    int c = threadIdx.x + i * 256;
    x[i] = h[base + c] + add[base + c];
    s += x[i];
    q += x[i] * x[i];
  }
  block_reduce_sum2(s, q);
  float mean = s * (1.0f / H);
  float var = q * (1.0f / H) - mean * mean;
  float inv = rsqrtf(var + LNEPS);
#pragma unroll
  for (int i = 0; i < 3; i++) {
    int c = threadIdx.x + i * 256;
    h[base + c] = (x[i] - mean) * inv * g[c] + bta[c];
  }
}

// ---------------- split-bf16 MFMA GEMM: C = A[M,Kd] @ W[Kd,N] + bias ----------------
// 2x2 waves per block; per-wave tile (BM/2)x(BN/2); LDS rows padded to 80B.
template <int BM, int BN, bool GELU>
__global__ __launch_bounds__(256) void gemm_mfma_kernel(
    const float* __restrict__ A, const float* __restrict__ W,
    const float* __restrict__ bias, float* __restrict__ C, int N, int Kd) {
  constexpr int WTM = BM / 2, WTN = BN / 2;
  constexpr int FM = WTM / 16, FN = WTN / 16;
  constexpr int STRIDE = 40;  // shorts per LDS row (80B: 32 data + 16B pad)
  __shared__ short Ah[BM * STRIDE];
  __shared__ short Al[BM * STRIDE];
  __shared__ short Wh[BN * STRIDE];
  __shared__ short Wl[BN * STRIDE];
  int tid = threadIdx.x;
  int lane = tid & 63, wid = tid >> 6;
  int wr = wid >> 1, wc = wid & 1;
  int bm = blockIdx.y * BM, bn = blockIdx.x * BN;
  f32x4 acc[FM][FN] = {};

  for (int k0 = 0; k0 < Kd; k0 += 32) {
    // ---- global load + convert (registers) ----
    alignas(16) unsigned short ahb[16], alb[16], whb[16], wlb[16];
    int am, ak, wn, wk;
    if constexpr (BM == 128) {
      am = tid >> 1; ak = (tid & 1) * 16;
      const float* ap = A + (size_t)(bm + am) * Kd + k0 + ak;
      float av[16];
      *(float4*)&av[0]  = *(const float4*)(ap + 0);
      *(float4*)&av[4]  = *(const float4*)(ap + 4);
      *(float4*)&av[8]  = *(const float4*)(ap + 8);
      *(float4*)&av[12] = *(const float4*)(ap + 12);
#pragma unroll
      for (int q = 0; q < 16; q++) split_bf16(av[q], ahb[q], alb[q]);
      wn = tid & 127; wk = (tid >> 7) * 16;
      const float* wp = W + (size_t)(k0 + wk) * N + bn + wn;
#pragma unroll
      for (int q = 0; q < 16; q++) {
        float wv = wp[(size_t)q * N];
        split_bf16(wv, whb[q], wlb[q]);
      }
    } else {
      am = tid >> 2; ak = (tid & 3) * 8;
      const float* ap = A + (size_t)(bm + am) * Kd + k0 + ak;
      float av[8];
      *(float4*)&av[0] = *(const float4*)(ap + 0);
      *(float4*)&av[4] = *(const float4*)(ap + 4);
#pragma unroll
      for (int q = 0; q < 8; q++) split_bf16(av[q], ahb[q], alb[q]);
      wn = tid & 63; wk = (tid >> 6) * 8;
      const float* wp = W + (size_t)(k0 + wk) * N + bn + wn;
#pragma unroll
      for (int q = 0; q < 8; q++) {
        float wv = wp[(size_t)q * N];
        split_bf16(wv, whb[q], wlb[q]);
      }
    }
    __syncthreads();  // previous compute done reading LDS
    if constexpr (BM == 128) {
      *(uint4*)&Ah[am * STRIDE + ak]     = *(uint4*)&ahb[0];
      *(uint4*)&Ah[am * STRIDE + ak + 8] = *(uint4*)&ahb[8];
      *(uint4*)&Al[am * STRIDE + ak]     = *(uint4*)&alb[0];
      *(uint4*)&Al[am * STRIDE + ak + 8] = *(uint4*)&alb[8];
      *(uint4*)&Wh[wn * STRIDE + wk]     = *(uint4*)&whb[0];
      *(uint4*)&Wh[wn * STRIDE + wk + 8] = *(uint4*)&whb[8];
      *(uint4*)&Wl[wn * STRIDE + wk]     = *(uint4*)&wlb[0];
      *(uint4*)&Wl[wn * STRIDE + wk + 8] = *(uint4*)&wlb[8];
    } else {
      *(uint4*)&Ah[am * STRIDE + ak] = *(uint4*)&ahb[0];
      *(uint4*)&Al[am * STRIDE + ak] = *(uint4*)&alb[0];
      *(uint4*)&Wh[wn * STRIDE + wk] = *(uint4*)&whb[0];
      *(uint4*)&Wl[wn * STRIDE + wk] = *(uint4*)&wlb[0];
    }
    __syncthreads();
    // ---- fragment loads + MFMA ----
    bf16x8 af_h[FM], af_l[FM], wf_h[FN], wf_l[FN];
    int lr = lane & 15, lg = lane >> 4;
#pragma unroll
    for (int i = 0; i < FM; i++) {
      int e = (wr * WTM + i * 16 + lr) * STRIDE + lg * 8;
      af_h[i] = *(const bf16x8*)&Ah[e];
      af_l[i] = *(const bf16x8*)&Al[e];
    }
#pragma unroll
    for (int j = 0; j < FN; j++) {
      int e = (wc * WTN + j * 16 + lr) * STRIDE + lg * 8;
      wf_h[j] = *(const bf16x8*)&Wh[e];
      wf_l[j] = *(const bf16x8*)&Wl[e];
    }
#pragma unroll
    for (int i = 0; i < FM; i++)
#pragma unroll
      for (int j = 0; j < FN; j++) {
        acc[i][j] = __builtin_amdgcn_mfma_f32_16x16x32_bf16(af_h[i], wf_h[j], acc[i][j], 0, 0, 0);
        acc[i][j] = __builtin_amdgcn_mfma_f32_16x16x32_bf16(af_l[i], wf_h[j], acc[i][j], 0, 0, 0);
        acc[i][j] = __builtin_amdgcn_mfma_f32_16x16x32_bf16(af_h[i], wf_l[j], acc[i][j], 0, 0, 0);
      }
  }
  // ---- epilogue: bias (+ optional exact GELU), scalar stores ----
  int lr = lane & 15, lg = lane >> 4;
#pragma unroll
  for (int i = 0; i < FM; i++) {
#pragma unroll
    for (int j = 0; j < FN; j++) {
      int row = bm + wr * WTM + i * 16 + lg * 4;
      int col = bn + wc * WTN + j * 16 + lr;
      float bv = bias[col];
#pragma unroll
      for (int r = 0; r < 4; r++) {
        float v = acc[i][j][r] + bv;
        if (GELU) v = 0.5f * v * (1.0f + erff(v * 0.70710678118654752f));
        C[(size_t)(row + r) * N + col] = v;
      }
    }
  }
}

// ---------------- S = Q K^T * scale + mask bias ----------------
__global__ __launch_bounds__(256) void qk_kernel(
    const float* __restrict__ qkv, const int* __restrict__ mask,
    float* __restrict__ S) {
  int bh = blockIdx.z;
  int b = bh / NH, hh = bh % NH;
  int i0 = blockIdx.y * 64, j0 = blockIdx.x * 64;
  __shared__ float Qs[64][64];
  __shared__ float Ks[64][64];
  int tid = threadIdx.x;
  int r = tid >> 2;
  int cseg = (tid & 3) * 16;
  const float* qbase = qkv + (size_t)(b * T + i0 + r) * (3 * H) + hh * DH;
  const float* kbase = qkv + (size_t)(b * T + j0 + r) * (3 * H) + H + hh * DH;
#pragma unroll
  for (int ss = 0; ss < 4; ss++) {
    int c = cseg + ss * 4;
    float4 qa = *(const float4*)(qbase + c);
    float4 ka = *(const float4*)(kbase + c);
    Qs[c + 0][r] = qa.x; Qs[c + 1][r] = qa.y; Qs[c + 2][r] = qa.z; Qs[c + 3][r] = qa.w;
    Ks[c + 0][r] = ka.x; Ks[c + 1][r] = ka.y; Ks[c + 2][r] = ka.z; Ks[c + 3][r] = ka.w;
  }
  __syncthreads();
  int tx = tid & 15, ty = tid >> 4;
  float acc[4][4] = {};
#pragma unroll 4
  for (int d = 0; d < 64; d++) {
    float a_[4], b_[4];
    *(float4*)a_ = *(const float4*)&Qs[d][ty * 4];
    *(float4*)b_ = *(const float4*)&Ks[d][tx * 4];
#pragma unroll
    for (int i = 0; i < 4; i++)
#pragma unroll
      for (int j = 0; j < 4; j++)
        acc[i][j] = fmaf(a_[i], b_[j], acc[i][j]);
  }
  float bj[4];
#pragma unroll
  for (int q = 0; q < 4; q++)
    bj[q] = (1.0f - (float)mask[b * T + j0 + tx * 4 + q]) * NEGB;
#pragma unroll
  for (int i = 0; i < 4; i++) {
    int gi = i0 + ty * 4 + i;
    int gj = j0 + tx * 4;
    float4 o;
    o.x = acc[i][0] * INV_SQRT_DH + bj[0];
    o.y = acc[i][1] * INV_SQRT_DH + bj[1];
    o.z = acc[i][2] * INV_SQRT_DH + bj[2];
    o.w = acc[i][3] * INV_SQRT_DH + bj[3];
    *(float4*)(S + ((size_t)bh * T + gi) * T + gj) = o;
  }
}

// ---------------- row softmax ----------------
__global__ __launch_bounds__(128) void softmax_kernel(float* __restrict__ S) {
  size_t row = blockIdx.x;
  float* p = S + row * T;
  int tid = threadIdx.x;
  float4 v = *(float4*)(p + tid * 4);
  float m = fmaxf(fmaxf(v.x, v.y), fmaxf(v.z, v.w));
#pragma unroll
  for (int off = 32; off > 0; off >>= 1) m = fmaxf(m, __shfl_xor(m, off));
  __shared__ float redm[2];
  __shared__ float reds[2];
  int wid = tid >> 6;
  if ((tid & 63) == 0) redm[wid] = m;
  __syncthreads();
  m = fmaxf(redm[0], redm[1]);
  v.x = __expf(v.x - m);
  v.y = __expf(v.y - m);
  v.z = __expf(v.z - m);
  v.w = __expf(v.w - m);
  float s = v.x + v.y + v.z + v.w;
  s = wave_sum_f(s);
  if ((tid & 63) == 0) reds[wid] = s;
  __syncthreads();
  s = reds[0] + reds[1];
  float inv = 1.0f / s;
  v.x *= inv; v.y *= inv; v.z *= inv; v.w *= inv;
  *(float4*)(p + tid * 4) = v;
}

// ---------------- ctx = P * V ----------------
__global__ __launch_bounds__(256) void pv_kernel(
    const float* __restrict__ S, const float* __restrict__ qkv,
    float* __restrict__ ctx) {
  int bh = blockIdx.y;
  int b = bh / NH, hh = bh % NH;
  int i0 = blockIdx.x * 64;
  __shared__ float Ps[64][68];
  __shared__ float Vs[64][64];
  int tid = threadIdx.x;
  int r = tid >> 2;
  int cseg = (tid & 3) * 16;
  int tx = tid & 15, ty = tid >> 4;
  float acc[4][4] = {};
  const float* srow = S + ((size_t)bh * T + i0 + r) * T;
  const float* vbase = qkv + (size_t)(b * T) * (3 * H) + 2 * H + hh * DH;
  for (int k0 = 0; k0 < T; k0 += 64) {
    __syncthreads();
#pragma unroll
    for (int ss = 0; ss < 4; ss++) {
      int c = cseg + ss * 4;
      *(float4*)&Ps[r][c] = *(const float4*)(srow + k0 + c);
      *(float4*)&Vs[r][c] = *(const float4*)(vbase + (size_t)(k0 + r) * (3 * H) + c);
    }
    __syncthreads();
#pragma unroll
    for (int kk = 0; kk < 64; kk += 4) {
      float p_[4][4], v_[4][4];
#pragma unroll
      for (int i = 0; i < 4; i++)
        *(float4*)p_[i] = *(const float4*)&Ps[ty * 4 + i][kk];
#pragma unroll
      for (int s = 0; s < 4; s++)
        *(float4*)v_[s] = *(const float4*)&Vs[kk + s][tx * 4];
#pragma unroll
      for (int i = 0; i < 4; i++)
#pragma unroll
        for (int s = 0; s < 4; s++)
#pragma unroll
          for (int j = 0; j < 4; j++)
            acc[i][j] = fmaf(p_[i][s], v_[s][j], acc[i][j]);
    }
  }
#pragma unroll
  for (int i = 0; i < 4; i++) {
    int gi = i0 + ty * 4 + i;
    float* cp = ctx + (size_t)(b * T + gi) * H + hh * DH + tx * 4;
    float4 o;
    o.x = acc[i][0]; o.y = acc[i][1]; o.z = acc[i][2]; o.w = acc[i][3];
    *(float4*)cp = o;
  }
}

// ---------------- classifier ----------------
__global__ __launch_bounds__(256) void classifier_kernel(
    const float* __restrict__ h, const float* __restrict__ Wc,
    const float* __restrict__ bc, float* __restrict__ em) {
  int id = blockIdx.x * 256 + threadIdx.x;
  if (id >= BT * K) return;
  int row = id / K, k = id % K;
  float acc = bc[k];
  const float* hr = h + (size_t)row * H;
  for (int d = 0; d < H; d++) acc = fmaf(hr[d], Wc[d * K + k], acc);
  em[id] = acc;
}

// ---------------- fused CRF nll + viterbi (role per block) ----------------
__global__ __launch_bounds__(64) void crf_fused_kernel(
    const float* __restrict__ em, const int* __restrict__ labels,
    const int* __restrict__ mask, const float* __restrict__ start,
    const float* __restrict__ endv, const float* __restrict__ trans,
    float* __restrict__ parts, float* __restrict__ outdec) {
  __shared__ float em_s[T * K];                 // 43008 B
  __shared__ int mask_s[T];                     // 2048 B
  __shared__ unsigned char hist_s[(T - 1) * K]; // 10731 B
  __shared__ float sc_s[32];
  int b = blockIdx.x & 3;
  int role = blockIdx.x >> 2;
  int j = threadIdx.x;
  const float* eb = em + (size_t)b * T * K;
  for (int i = j; i < T * K / 4; i += 64)
    ((float4*)em_s)[i] = ((const float4*)eb)[i];
  for (int i = j; i < T; i += 64) mask_s[i] = mask[b * T + i];
  __syncthreads();
  bool act = (j < K);
  float tr[K];
  if (act) {
#pragma unroll
    for (int i = 0; i < K; i++) tr[i] = trans[i * K + j];
  } else {
#pragma unroll
    for (int i = 0; i < K; i++) tr[i] = 0.f;
  }

  if (role == 0) {
    // ---- CRF forward / nll ----
    const int* tb = labels + b * T;
    float numloc = 0.f;
    int cnt = 0;
    for (int t = j; t < T; t += 64) {
      cnt += mask_s[t];
      if (t >= 1 && mask_s[t]) {
        int tp = tb[t - 1], tc = tb[t];
        numloc += trans[tp * K + tc] + em_s[t * K + tc];
      }
    }
    float num = wave_sum_f(numloc);
    int cnttot = wave_sum_i(cnt);
    float alpha = -3.0e38f;
    if (act) alpha = start[j] + em_s[j];
    for (int t = 1; t < T; t++) {
      if (mask_s[t]) {
        float vals[K];
        float m = -3.0e38f;
#pragma unroll
        for (int i = 0; i < K; i++) {
          float v = __shfl(alpha, i) + tr[i];
          vals[i] = v;
          m = fmaxf(m, v);
        }
        float ssum = 0.f;
#pragma unroll
        for (int i = 0; i < K; i++) ssum += __expf(vals[i] - m);
        float emv = act ? em_s[t * K + j] : 0.f;
        float nxt = __logf(ssum) + m + emv;
        if (act) alpha = nxt;
      }
    }
    float aj = act ? (alpha + endv[j]) : -3.0e38f;
    float mm = aj;
#pragma unroll
    for (int off = 32; off > 0; off >>= 1) mm = fmaxf(mm, __shfl_xor(mm, off));
    float e = act ? __expf(aj - mm) : 0.f;
    float s = wave_sum_f(e);
    float den = __logf(s) + mm;
    if (j == 0) {
      int tag0 = tb[0];
      int lastidx = cnttot - 1;
      float numtot = num + start[tag0] + em_s[tag0] + endv[tb[lastidx]];
      parts[b] = numtot - den;
    }
  } else {
    // ---- Viterbi ----
    float score = -3.0e38f;
    if (act) score = start[j] + em_s[j];
    for (int t = 1; t < T; t++) {
      int m = mask_s[t];
      float best = -3.0e38f;
      int bi = 0;
#pragma unroll
      for (int i = 0; i < K; i++) {
        float v = __shfl(score, i) + tr[i];
        if (v > best) { best = v; bi = i; }  // first-max semantics
      }
      if (act) {
        hist_s[(t - 1) * K + j] = (unsigned char)(m ? bi : j);
        if (m) score = best + em_s[t * K + j];
      }
    }
    if (act) sc_s[j] = score + endv[j];
    __syncthreads();
    if (j == 0) {
      float best = -3.0e38f;
      int cur = 0;
#pragma unroll
      for (int i = 0; i < K; i++)
        if (sc_s[i] > best) { best = sc_s[i]; cur = i; }
      outdec[b * T + (T - 1)] = (float)cur;
      for (int t = T - 1; t >= 1; t--) {
        cur = hist_s[(t - 1) * K + cur];
        outdec[b * T + (t - 1)] = (float)cur;
      }
    }
  }
}

__global__ void nll_final_kernel(const float* __restrict__ parts,
                                 float* __restrict__ out) {
  out[0] = -0.25f * (parts[0] + parts[1] + parts[2] + parts[3]);
}

// ---------------- host launcher ----------------
extern "C" void kernel_launch(void* const* d_in, const int* in_sizes, int n_in,
                              void* d_out, int out_size, void* d_ws, size_t ws_size,
                              hipStream_t stream) {
  (void)in_sizes; (void)n_in; (void)out_size; (void)ws_size;
  const int* ids    = (const int*)d_in[0];
  const int* amask  = (const int*)d_in[1];
  const int* labels = (const int*)d_in[3];
  const float* wemb = (const float*)d_in[4];
  const float* pemb = (const float*)d_in[5];
  const float* temb = (const float*)d_in[6];
  const float* eg   = (const float*)d_in[7];
  const float* ebta = (const float*)d_in[8];
  const float* Wqkv = (const float*)d_in[9];
  const float* bqkv = (const float*)d_in[10];
  const float* Wo   = (const float*)d_in[11];
  const float* bo   = (const float*)d_in[12];
  const float* ln1g = (const float*)d_in[13];
  const float* ln1b = (const float*)d_in[14];
  const float* W1   = (const float*)d_in[15];
  const float* b1   = (const float*)d_in[16];
  const float* W2   = (const float*)d_in[17];
  const float* b2   = (const float*)d_in[18];
  const float* ln2g = (const float*)d_in[19];
  const float* ln2b = (const float*)d_in[20];
  const float* Wc   = (const float*)d_in[21];
  const float* bc   = (const float*)d_in[22];
  const float* cst  = (const float*)d_in[23];
  const float* cen  = (const float*)d_in[24];
  const float* ctr  = (const float*)d_in[25];
  float* out = (float*)d_out;

  float* ws   = (float*)d_ws;
  float* h    = ws;
  float* qkv  = h + (size_t)BT * H;
  float* ctx  = qkv + (size_t)BT * 3 * H;
  float* tmp  = ctx + (size_t)BT * H;
  float* big  = tmp + (size_t)BT * H;
  float* em   = big + (size_t)B * NH * T * T;
  float* parts = em + (size_t)BT * K;

  embed_ln_kernel<<<BT, 256, 0, stream>>>(ids, wemb, pemb, temb, eg, ebta, h);

  for (int l = 0; l < NLAYER; l++) {
    const float* wqkv_l = Wqkv + (size_t)l * H * 3 * H;
    const float* bqkv_l = bqkv + (size_t)l * 3 * H;
    const float* wo_l   = Wo + (size_t)l * H * H;
    const float* bo_l   = bo + (size_t)l * H;
    const float* w1_l   = W1 + (size_t)l * H * 4 * H;
    const float* b1_l   = b1 + (size_t)l * 4 * H;
    const float* w2_l   = W2 + (size_t)l * 4 * H * H;
    const float* b2_l   = b2 + (size_t)l * H;

    gemm_mfma_kernel<128, 128, false><<<dim3(3 * H / 128, BT / 128), 256, 0, stream>>>(
        h, wqkv_l, bqkv_l, qkv, 3 * H, H);
    qk_kernel<<<dim3(T / 64, T / 64, B * NH), 256, 0, stream>>>(qkv, amask, big);
    softmax_kernel<<<B * NH * T, 128, 0, stream>>>(big);
    pv_kernel<<<dim3(T / 64, B * NH), 256, 0, stream>>>(big, qkv, ctx);
    gemm_mfma_kernel<64, 64, false><<<dim3(H / 64, BT / 64), 256, 0, stream>>>(
        ctx, wo_l, bo_l, tmp, H, H);
    add_ln_kernel<<<BT, 256, 0, stream>>>(h, tmp, ln1g + (size_t)l * H, ln1b + (size_t)l * H);
    gemm_mfma_kernel<128, 128, true><<<dim3(4 * H / 128, BT / 128), 256, 0, stream>>>(
        h, w1_l, b1_l, big, 4 * H, H);
    gemm_mfma_kernel<64, 64, false><<<dim3(H / 64, BT / 64), 256, 0, stream>>>(
        big, w2_l, b2_l, tmp, H, 4 * H);
    add_ln_kernel<<<BT, 256, 0, stream>>>(h, tmp, ln2g + (size_t)l * H, ln2b + (size_t)l * H);
  }

  classifier_kernel<<<(BT * K + 255) / 256, 256, 0, stream>>>(h, Wc, bc, em);
  crf_fused_kernel<<<8, 64, 0, stream>>>(em, labels, amask, cst, cen, ctr, parts, out + 1);
  nll_final_kernel<<<1, 1, 0, stream>>>(parts, out);
}